// Round 8
// baseline (546.707 us; speedup 1.0000x reference)
//
#include <hip/hip_runtime.h>
#include <hip/hip_bf16.h>

#define N_NODES 50000
#define N_EDGES 800000
#define N_BUCKETS 64
#define M_PAD 50048  // 391 * 128, pads GEMM A-inputs so staging never reads OOB
#define SCAN_NB 196  // ceil(50000 / 256)

typedef short short8 __attribute__((ext_vector_type(8)));
typedef float floatx4 __attribute__((ext_vector_type(4)));

// ---- bf16 helpers (RNE) ---------------------------------------------------
__device__ __forceinline__ unsigned short f2bf(float f) {
    unsigned u = __float_as_uint(f);
    unsigned r = (u + 0x7fff + ((u >> 16) & 1)) >> 16;
    return (unsigned short)r;
}
__device__ __forceinline__ float bf2f(unsigned short h) {
    return __uint_as_float(((unsigned)h) << 16);
}
__device__ __forceinline__ void expand2(unsigned u, float& lo, float& hi) {
    lo = __uint_as_float(u << 16);
    hi = __uint_as_float(u & 0xffff0000u);
}
__device__ __forceinline__ void accum8(float* a, uint4 g, float w) {
    float lo, hi;
    expand2(g.x, lo, hi); a[0] += lo * w; a[1] += hi * w;
    expand2(g.y, lo, hi); a[2] += lo * w; a[3] += hi * w;
    expand2(g.z, lo, hi); a[4] += lo * w; a[5] += hi * w;
    expand2(g.w, lo, hi); a[6] += lo * w; a[7] += hi * w;
}

// async global->LDS, 16B per lane; lds dest = wave-uniform base + lane*16
__device__ __forceinline__ void gload16(const void* gp, void* lp) {
    __builtin_amdgcn_global_load_lds(
        (const __attribute__((address_space(1))) unsigned int*)gp,
        (__attribute__((address_space(3))) unsigned int*)lp,
        16, 0, 0);
}

// ---------------------------------------------------------------------------
__global__ void k_init(int* __restrict__ cnt, float* __restrict__ gb) {
    int i = blockIdx.x * blockDim.x + threadIdx.x;
    if (i < N_NODES) cnt[i] = 0;
    if (i < N_BUCKETS * 256) gb[i] = 0.0f;
}

__global__ void k_count(const int* __restrict__ col, int* __restrict__ cnt) {
    int e = blockIdx.x * blockDim.x + threadIdx.x;
    if (e < N_EDGES) atomicAdd(&cnt[col[e]], 1);
}

// --- 3-phase hierarchical exclusive scan of cnt -> off/cursor --------------
__global__ __launch_bounds__(256) void k_scanA(const int* __restrict__ cnt,
                                               int* __restrict__ bsum) {
    __shared__ int red[256];
    int t = threadIdx.x;
    int i = blockIdx.x * 256 + t;
    red[t] = (i < N_NODES) ? cnt[i] : 0;
    __syncthreads();
    for (int d = 128; d > 0; d >>= 1) {
        if (t < d) red[t] += red[t + d];
        __syncthreads();
    }
    if (t == 0) bsum[blockIdx.x] = red[0];
}

__global__ __launch_bounds__(256) void k_scanB(const int* __restrict__ bsum,
                                               int* __restrict__ bbase,
                                               int* __restrict__ off) {
    __shared__ int sc[256];
    int t = threadIdx.x;
    sc[t] = (t < SCAN_NB) ? bsum[t] : 0;
    __syncthreads();
    for (int d = 1; d < 256; d <<= 1) {
        int v = 0;
        if (t >= d) v = sc[t - d];
        __syncthreads();
        if (t >= d) sc[t] += v;
        __syncthreads();
    }
    if (t < SCAN_NB) bbase[t] = sc[t] - bsum[t];  // exclusive
    if (t == 0) off[N_NODES] = N_EDGES;
}

__global__ __launch_bounds__(256) void k_scanC(const int* __restrict__ cnt,
                                               const int* __restrict__ bbase,
                                               int* __restrict__ off,
                                               int* __restrict__ cursor,
                                               float* __restrict__ dinv) {
    __shared__ int sc[256];
    int t = threadIdx.x;
    int i = blockIdx.x * 256 + t;
    int c = (i < N_NODES) ? cnt[i] : 0;
    sc[t] = c;
    __syncthreads();
    for (int d = 1; d < 256; d <<= 1) {
        int v = 0;
        if (t >= d) v = sc[t - d];
        __syncthreads();
        if (t >= d) sc[t] += v;
        __syncthreads();
    }
    if (i < N_NODES) {
        int excl = sc[t] - c + bbase[blockIdx.x];
        off[i] = excl;
        cursor[i] = excl;
        dinv[i] = 1.0f / sqrtf((float)(c + 1));
    }
}

__global__ void k_fill(const int* __restrict__ row, const int* __restrict__ col,
                       const float* __restrict__ dinv, int* __restrict__ cursor,
                       int2* __restrict__ epack) {
    int e = blockIdx.x * blockDim.x + threadIdx.x;
    if (e >= N_EDGES) return;
    int v = col[e];
    int p = atomicAdd(&cursor[v], 1);
    int r = row[e];
    epack[p] = make_int2(r, __float_as_int(dinv[r]));
}

// W [K][N] fp32 -> transposed split bf16 WT{h,l} [N][K] (weights stay exact)
__global__ void k_prepW(const float* __restrict__ W,
                        unsigned short* __restrict__ Th,
                        unsigned short* __restrict__ Tl, int K, int N) {
    int idx = blockIdx.x * blockDim.x + threadIdx.x;
    if (idx >= K * N) return;
    int n = idx / K, k = idx - n * K;
    float v = W[(size_t)k * N + n];
    unsigned short h = f2bf(v);
    Th[idx] = h;
    Tl[idx] = f2bf(v - bf2f(h));
}

// x fp32 -> bf16
__global__ void k_prepX(const float* __restrict__ x, unsigned short* __restrict__ xb) {
    int i = blockIdx.x * blockDim.x + threadIdx.x;
    if (i < N_NODES * 128) xb[i] = f2bf(x[i]);
}

// aggregation over bf16 rows, fp32 accum:
//   res[v] = dinv[v] * ( x[v]*dinv[v] + sum_j x[r_j]*dinv[r_j] )
// POOL=0: store bf16 row. POOL=1: bias+relu, bucketed mean-pool partial.
// Lanes: DIM/8 per node, 16B per lane. Edge loop: flat unroll 8 (8 gathers
// in flight; R5's rotating-prefetch variant regressed, this is the flat form)
// + unroll-4 step + scalar tail.
template <int DIM, int POOL>
__global__ __launch_bounds__(256) void k_aggb(
    const unsigned short* __restrict__ xb, const int* __restrict__ off,
    const int2* __restrict__ epack, const float* __restrict__ dinv,
    const float* __restrict__ bias, unsigned short* __restrict__ outb,
    float* __restrict__ gb) {
    const int LPN = DIM / 8;
    const int NPB = 256 / LPN;
    __shared__ float gpart[256];
    if (POOL) {
        gpart[threadIdx.x] = 0.0f;
        __syncthreads();
    }
    int v = blockIdx.x * NPB + threadIdx.x / LPN;   // grid divides N exactly
    int f = (threadIdx.x % LPN) * 8;
    float dv = dinv[v];
    const unsigned short* __restrict__ xf = xb + f;
    float a0[8], a1[8], a2[8], a3[8];
    {
        uint4 sv = *(const uint4*)&xf[(size_t)v * DIM];
        float e0, e1;
        expand2(sv.x, e0, e1); a0[0] = e0 * dv; a0[1] = e1 * dv;
        expand2(sv.y, e0, e1); a0[2] = e0 * dv; a0[3] = e1 * dv;
        expand2(sv.z, e0, e1); a0[4] = e0 * dv; a0[5] = e1 * dv;
        expand2(sv.w, e0, e1); a0[6] = e0 * dv; a0[7] = e1 * dv;
#pragma unroll
        for (int i = 0; i < 8; ++i) { a1[i] = 0.f; a2[i] = 0.f; a3[i] = 0.f; }
    }
    int s = off[v], e = off[v + 1];
    int j = s;
    for (; j + 8 <= e; j += 8) {
        int2 p0 = epack[j + 0];
        int2 p1 = epack[j + 1];
        int2 p2 = epack[j + 2];
        int2 p3 = epack[j + 3];
        int2 p4 = epack[j + 4];
        int2 p5 = epack[j + 5];
        int2 p6 = epack[j + 6];
        int2 p7 = epack[j + 7];
        uint4 g0 = *(const uint4*)&xf[(size_t)p0.x * DIM];
        uint4 g1 = *(const uint4*)&xf[(size_t)p1.x * DIM];
        uint4 g2 = *(const uint4*)&xf[(size_t)p2.x * DIM];
        uint4 g3 = *(const uint4*)&xf[(size_t)p3.x * DIM];
        uint4 g4 = *(const uint4*)&xf[(size_t)p4.x * DIM];
        uint4 g5 = *(const uint4*)&xf[(size_t)p5.x * DIM];
        uint4 g6 = *(const uint4*)&xf[(size_t)p6.x * DIM];
        uint4 g7 = *(const uint4*)&xf[(size_t)p7.x * DIM];
        accum8(a0, g0, __int_as_float(p0.y));
        accum8(a1, g1, __int_as_float(p1.y));
        accum8(a2, g2, __int_as_float(p2.y));
        accum8(a3, g3, __int_as_float(p3.y));
        accum8(a0, g4, __int_as_float(p4.y));
        accum8(a1, g5, __int_as_float(p5.y));
        accum8(a2, g6, __int_as_float(p6.y));
        accum8(a3, g7, __int_as_float(p7.y));
    }
    if (j + 4 <= e) {
        int2 p0 = epack[j + 0];
        int2 p1 = epack[j + 1];
        int2 p2 = epack[j + 2];
        int2 p3 = epack[j + 3];
        uint4 g0 = *(const uint4*)&xf[(size_t)p0.x * DIM];
        uint4 g1 = *(const uint4*)&xf[(size_t)p1.x * DIM];
        uint4 g2 = *(const uint4*)&xf[(size_t)p2.x * DIM];
        uint4 g3 = *(const uint4*)&xf[(size_t)p3.x * DIM];
        accum8(a0, g0, __int_as_float(p0.y));
        accum8(a1, g1, __int_as_float(p1.y));
        accum8(a2, g2, __int_as_float(p2.y));
        accum8(a3, g3, __int_as_float(p3.y));
        j += 4;
    }
    for (; j < e; ++j) {
        int2 p = epack[j];
        uint4 g = *(const uint4*)&xf[(size_t)p.x * DIM];
        accum8(a0, g, __int_as_float(p.y));
    }
    float acc[8];
#pragma unroll
    for (int i = 0; i < 8; ++i)
        acc[i] = ((a0[i] + a1[i]) + (a2[i] + a3[i])) * dv;
    if (!POOL) {
        uint4 o;
        o.x = (unsigned)f2bf(acc[0]) | ((unsigned)f2bf(acc[1]) << 16);
        o.y = (unsigned)f2bf(acc[2]) | ((unsigned)f2bf(acc[3]) << 16);
        o.z = (unsigned)f2bf(acc[4]) | ((unsigned)f2bf(acc[5]) << 16);
        o.w = (unsigned)f2bf(acc[6]) | ((unsigned)f2bf(acc[7]) << 16);
        *(uint4*)&outb[(size_t)v * DIM + f] = o;
    } else {
#pragma unroll
        for (int i = 0; i < 8; ++i) {
            float r = fmaxf(acc[i] + bias[f + i], 0.0f);
            atomicAdd(&gpart[f + i], r);
        }
        __syncthreads();
        atomicAdd(&gb[(blockIdx.x & (N_BUCKETS - 1)) * 256 + threadIdx.x],
                  gpart[threadIdx.x]);
    }
}

// ---------------------------------------------------------------------------
// bf16-A x split-bf16-B MFMA GEMM: C[M,N] = A[M,K] @ (Bh+Bl)[K,N] (+bias)(relu)
// B pre-transposed [N][K]. 128x128 tile, BK=32, double-buffered LDS.
// LDS k-chunks swizzled by (row>>1)&3 to break the 64B-row-stride conflicts.
template <int BIAS, int RELU>
__global__ __launch_bounds__(256) void k_gemm_b(
    const unsigned short* __restrict__ A,
    const unsigned short* __restrict__ Bh, const unsigned short* __restrict__ Bl,
    const float* __restrict__ bias, unsigned short* __restrict__ C,
    int M, int K, int N) {
    __shared__ unsigned short As[2][128 * 32];
    __shared__ unsigned short BsH[2][128 * 32];
    __shared__ unsigned short BsL[2][128 * 32];
    int tid = threadIdx.x;
    int lane = tid & 63;
    int w = tid >> 6;
    int wr = w & 1, wc = w >> 1;
    int bm = blockIdx.x * 128, bn = blockIdx.y * 128;

    floatx4 acc[4][4];
    floatx4 zero = {0.f, 0.f, 0.f, 0.f};
#pragma unroll
    for (int t = 0; t < 4; ++t)
#pragma unroll
        for (int u = 0; u < 4; ++u) acc[t][u] = zero;

    int c0 = w * 2, c1 = c0 + 1;
    int srow = lane >> 2;
    int kg = ((lane & 3) - ((lane >> 3) & 3)) & 3;  // global k-chunk (inverse swizzle)
    int kc = kg * 8;
    const unsigned short* Ap0 = A + (size_t)(bm + c0 * 16 + srow) * K + kc;
    const unsigned short* Ap1 = A + (size_t)(bm + c1 * 16 + srow) * K + kc;
    const unsigned short* Bh0 = Bh + (size_t)(bn + c0 * 16 + srow) * K + kc;
    const unsigned short* Bh1 = Bh + (size_t)(bn + c1 * 16 + srow) * K + kc;
    const unsigned short* Bl0 = Bl + (size_t)(bn + c0 * 16 + srow) * K + kc;
    const unsigned short* Bl1 = Bl + (size_t)(bn + c1 * 16 + srow) * K + kc;

    const int KT = K >> 5;
#define STAGE(half, k0)                                   \
    do {                                                  \
        gload16(Ap0 + (k0), &As[half][c0 * 512]);         \
        gload16(Ap1 + (k0), &As[half][c1 * 512]);         \
        gload16(Bh0 + (k0), &BsH[half][c0 * 512]);        \
        gload16(Bh1 + (k0), &BsH[half][c1 * 512]);        \
        gload16(Bl0 + (k0), &BsL[half][c0 * 512]);        \
        gload16(Bl1 + (k0), &BsL[half][c1 * 512]);        \
    } while (0)

    STAGE(0, 0);
    __syncthreads();

    int fr = lane & 15;            // m (A) / n (B) within 16-tile
    int fq = lane >> 4;            // k-chunk 0..3
    int cl = ((fq + (fr >> 1)) & 3) * 8;  // swizzled LDS k-chunk offset

    for (int kt = 0; kt < KT; ++kt) {
        int half = kt & 1;
        if (kt + 1 < KT) STAGE(1 - half, (kt + 1) * 32);
        short8 av[4], bhv[4], blv[4];
#pragma unroll
        for (int t = 0; t < 4; ++t) {
            av[t]  = *(const short8*)&As[half][(wr * 64 + t * 16 + fr) * 32 + cl];
            bhv[t] = *(const short8*)&BsH[half][(wc * 64 + t * 16 + fr) * 32 + cl];
            blv[t] = *(const short8*)&BsL[half][(wc * 64 + t * 16 + fr) * 32 + cl];
        }
#pragma unroll
        for (int t = 0; t < 4; ++t)
#pragma unroll
            for (int u = 0; u < 4; ++u) {
                acc[t][u] = __builtin_amdgcn_mfma_f32_16x16x32_bf16(av[t], bhv[u], acc[t][u], 0, 0, 0);
                acc[t][u] = __builtin_amdgcn_mfma_f32_16x16x32_bf16(av[t], blv[u], acc[t][u], 0, 0, 0);
            }
        __syncthreads();
    }
#undef STAGE

    // epilogue: C/D layout col = lane&15, row = (lane>>4)*4 + reg
#pragma unroll
    for (int u = 0; u < 4; ++u) {
        int colg = bn + wc * 64 + u * 16 + fr;
        float bv = BIAS ? bias[colg] : 0.0f;
#pragma unroll
        for (int t = 0; t < 4; ++t) {
#pragma unroll
            for (int r = 0; r < 4; ++r) {
                int rowg = bm + wr * 64 + t * 16 + fq * 4 + r;
                if (rowg < M) {
                    float o = acc[t][u][r] + bv;
                    if (RELU) o = fmaxf(o, 0.f);
                    C[(size_t)rowg * N + colg] = f2bf(o);
                }
            }
        }
    }
}

// tiny MLP; first reduces the 64 pool buckets
__global__ void k_mlp(const float* __restrict__ gb,
                      const float* __restrict__ Wf1, const float* __restrict__ bf1,
                      const float* __restrict__ Wf2, const float* __restrict__ bf2,
                      const float* __restrict__ Wf3, const float* __restrict__ bf3,
                      float* __restrict__ out) {
    __shared__ float s0[256], s1[128], s2[64];
    int t = threadIdx.x;
    float sum = 0.0f;
    for (int b = 0; b < N_BUCKETS; ++b) sum += gb[b * 256 + t];
    s0[t] = sum * (1.0f / (float)N_NODES);
    __syncthreads();
    if (t < 128) {
        float a = bf1[t];
        for (int k = 0; k < 256; ++k) a += s0[k] * Wf1[k * 128 + t];
        s1[t] = fmaxf(a, 0.0f);
    }
    __syncthreads();
    if (t < 64) {
        float a = bf2[t];
        for (int k = 0; k < 128; ++k) a += s1[k] * Wf2[k * 64 + t];
        s2[t] = fmaxf(a, 0.0f);
    }
    __syncthreads();
    if (t == 0) {
        float a = bf3[0];
        for (int k = 0; k < 64; ++k) a += s2[k] * Wf3[k];
        out[0] = a;
    }
}

extern "C" void kernel_launch(void* const* d_in, const int* in_sizes, int n_in,
                              void* d_out, int out_size, void* d_ws, size_t ws_size,
                              hipStream_t stream) {
    const float* x  = (const float*)d_in[0];
    const int* ei   = (const int*)d_in[1];
    const float* W1 = (const float*)d_in[2];
    const float* b1 = (const float*)d_in[3];
    const float* W2 = (const float*)d_in[4];
    const float* b2 = (const float*)d_in[5];
    const float* W3 = (const float*)d_in[6];
    const float* b3 = (const float*)d_in[7];
    const float* Wf1 = (const float*)d_in[8];
    const float* bf1 = (const float*)d_in[9];
    const float* Wf2 = (const float*)d_in[10];
    const float* bf2 = (const float*)d_in[11];
    const float* Wf3 = (const float*)d_in[12];
    const float* bf3 = (const float*)d_in[13];
    float* out = (float*)d_out;

    char* p = (char*)d_ws;
    auto alloc = [&](size_t bytes) {
        void* r = (void*)p;
        p += (bytes + 255) & ~((size_t)255);
        return r;
    };
    int*   cnt    = (int*)  alloc(N_NODES * sizeof(int));
    int*   off    = (int*)  alloc((N_NODES + 1) * sizeof(int));
    int*   cursor = (int*)  alloc(N_NODES * sizeof(int));
    int*   bsum   = (int*)  alloc(SCAN_NB * sizeof(int));
    int*   bbase  = (int*)  alloc(SCAN_NB * sizeof(int));
    float* dinv   = (float*)alloc(N_NODES * sizeof(float));
    int2*  epack  = (int2*) alloc((size_t)N_EDGES * sizeof(int2));
    float* gb     = (float*)alloc(N_BUCKETS * 256 * sizeof(float));
    unsigned short* W1h = (unsigned short*)alloc(128 * 256 * 2);
    unsigned short* W1l = (unsigned short*)alloc(128 * 256 * 2);
    unsigned short* W2h = (unsigned short*)alloc(256 * 512 * 2);
    unsigned short* W2l = (unsigned short*)alloc(256 * 512 * 2);
    unsigned short* W3h = (unsigned short*)alloc(512 * 256 * 2);
    unsigned short* W3l = (unsigned short*)alloc(512 * 256 * 2);
    unsigned short* xb = (unsigned short*)alloc((size_t)N_NODES * 128 * 2);
    unsigned short* t0 = (unsigned short*)alloc((size_t)M_PAD * 128 * 2);
    unsigned short* h1 = (unsigned short*)alloc((size_t)N_NODES * 256 * 2);
    unsigned short* t1 = (unsigned short*)alloc((size_t)M_PAD * 256 * 2);
    unsigned short* h2 = (unsigned short*)alloc((size_t)M_PAD * 512 * 2);
    unsigned short* t2 = (unsigned short*)alloc((size_t)N_NODES * 256 * 2);

    const int* row = ei;
    const int* col = ei + N_EDGES;

    const int NB = (N_NODES + 255) / 256;  // 196
    const int EB = (N_EDGES + 255) / 256;

    // CSR build + norm (hierarchical scan)
    k_init<<<NB, 256, 0, stream>>>(cnt, gb);
    k_count<<<EB, 256, 0, stream>>>(col, cnt);
    k_scanA<<<SCAN_NB, 256, 0, stream>>>(cnt, bsum);
    k_scanB<<<1, 256, 0, stream>>>(bsum, bbase, off);
    k_scanC<<<SCAN_NB, 256, 0, stream>>>(cnt, bbase, off, cursor, dinv);
    k_fill<<<EB, 256, 0, stream>>>(row, col, dinv, cursor, epack);

    // weight prep (transpose + exact split) and x -> bf16
    k_prepW<<<(128 * 256 + 255) / 256, 256, 0, stream>>>(W1, W1h, W1l, 128, 256);
    k_prepW<<<(256 * 512 + 255) / 256, 256, 0, stream>>>(W2, W2h, W2l, 256, 512);
    k_prepW<<<(512 * 256 + 255) / 256, 256, 0, stream>>>(W3, W3h, W3l, 512, 256);
    k_prepX<<<(N_NODES * 128 + 255) / 256, 256, 0, stream>>>(x, xb);

    const int M = N_NODES;
    const int MB = (M + 127) / 128; // 391

    // conv1: t0 = agg(xb); h1 = relu(t0@W1 + b1)
    k_aggb<128, 0><<<N_NODES / 16, 256, 0, stream>>>(
        xb, off, epack, dinv, nullptr, t0, nullptr);
    {
        dim3 grid(MB, 256 / 128);
        k_gemm_b<1, 1><<<grid, 256, 0, stream>>>(t0, W1h, W1l, b1, h1, M, 128, 256);
    }
    // conv2: t1 = agg(h1); h2 = relu(t1@W2 + b2)
    k_aggb<256, 0><<<N_NODES / 8, 256, 0, stream>>>(
        h1, off, epack, dinv, nullptr, t1, nullptr);
    {
        dim3 grid(MB, 512 / 128);
        k_gemm_b<1, 1><<<grid, 256, 0, stream>>>(t1, W2h, W2l, b2, h2, M, 256, 512);
    }
    // conv3: t2 = h2@W3; fused agg + bias + relu + bucketed mean-pool
    {
        dim3 grid(MB, 256 / 128);
        k_gemm_b<0, 0><<<grid, 256, 0, stream>>>(h2, W3h, W3l, nullptr, t2, M, 512, 256);
    }
    k_aggb<256, 1><<<N_NODES / 8, 256, 0, stream>>>(
        t2, off, epack, dinv, b3, nullptr, gb);

    // MLP (reduces buckets internally)
    k_mlp<<<1, 256, 0, stream>>>(gb, Wf1, bf1, Wf2, bf2, Wf3, bf3, out);
}

// Round 9
// 546.296 us; speedup vs baseline: 1.0008x; 1.0008x over previous
//
#include <hip/hip_runtime.h>
#include <hip/hip_bf16.h>

#define N_NODES 50000
#define N_EDGES 800000
#define N_BUCKETS 64
#define M_PAD 50048  // 391 * 128, pads GEMM A-inputs so staging never reads OOB
#define SCAN_NB 196  // ceil(50000 / 256)

typedef short short8 __attribute__((ext_vector_type(8)));
typedef float floatx4 __attribute__((ext_vector_type(4)));

// ---- bf16 helpers (RNE) ---------------------------------------------------
__device__ __forceinline__ unsigned short f2bf(float f) {
    unsigned u = __float_as_uint(f);
    unsigned r = (u + 0x7fff + ((u >> 16) & 1)) >> 16;
    return (unsigned short)r;
}
__device__ __forceinline__ float bf2f(unsigned short h) {
    return __uint_as_float(((unsigned)h) << 16);
}
__device__ __forceinline__ void expand2(unsigned u, float& lo, float& hi) {
    lo = __uint_as_float(u << 16);
    hi = __uint_as_float(u & 0xffff0000u);
}
__device__ __forceinline__ void accum8(float* a, uint4 g, float w) {
    float lo, hi;
    expand2(g.x, lo, hi); a[0] += lo * w; a[1] += hi * w;
    expand2(g.y, lo, hi); a[2] += lo * w; a[3] += hi * w;
    expand2(g.z, lo, hi); a[4] += lo * w; a[5] += hi * w;
    expand2(g.w, lo, hi); a[6] += lo * w; a[7] += hi * w;
}

// async global->LDS, 16B per lane; lds dest = wave-uniform base + lane*16
__device__ __forceinline__ void gload16(const void* gp, void* lp) {
    __builtin_amdgcn_global_load_lds(
        (const __attribute__((address_space(1))) unsigned int*)gp,
        (__attribute__((address_space(3))) unsigned int*)lp,
        16, 0, 0);
}

// ---------------------------------------------------------------------------
__global__ void k_init(int* __restrict__ cnt, float* __restrict__ gb) {
    int i = blockIdx.x * blockDim.x + threadIdx.x;
    if (i < N_NODES) cnt[i] = 0;
    if (i < N_BUCKETS * 256) gb[i] = 0.0f;
}

__global__ void k_count(const int* __restrict__ col, int* __restrict__ cnt) {
    int e = blockIdx.x * blockDim.x + threadIdx.x;
    if (e < N_EDGES) atomicAdd(&cnt[col[e]], 1);
}

// --- 3-phase hierarchical exclusive scan of cnt -> off/cursor --------------
__global__ __launch_bounds__(256) void k_scanA(const int* __restrict__ cnt,
                                               int* __restrict__ bsum) {
    __shared__ int red[256];
    int t = threadIdx.x;
    int i = blockIdx.x * 256 + t;
    red[t] = (i < N_NODES) ? cnt[i] : 0;
    __syncthreads();
    for (int d = 128; d > 0; d >>= 1) {
        if (t < d) red[t] += red[t + d];
        __syncthreads();
    }
    if (t == 0) bsum[blockIdx.x] = red[0];
}

__global__ __launch_bounds__(256) void k_scanB(const int* __restrict__ bsum,
                                               int* __restrict__ bbase,
                                               int* __restrict__ off) {
    __shared__ int sc[256];
    int t = threadIdx.x;
    sc[t] = (t < SCAN_NB) ? bsum[t] : 0;
    __syncthreads();
    for (int d = 1; d < 256; d <<= 1) {
        int v = 0;
        if (t >= d) v = sc[t - d];
        __syncthreads();
        if (t >= d) sc[t] += v;
        __syncthreads();
    }
    if (t < SCAN_NB) bbase[t] = sc[t] - bsum[t];  // exclusive
    if (t == 0) off[N_NODES] = N_EDGES;
}

__global__ __launch_bounds__(256) void k_scanC(const int* __restrict__ cnt,
                                               const int* __restrict__ bbase,
                                               int* __restrict__ off,
                                               int* __restrict__ cursor,
                                               float* __restrict__ dinv) {
    __shared__ int sc[256];
    int t = threadIdx.x;
    int i = blockIdx.x * 256 + t;
    int c = (i < N_NODES) ? cnt[i] : 0;
    sc[t] = c;
    __syncthreads();
    for (int d = 1; d < 256; d <<= 1) {
        int v = 0;
        if (t >= d) v = sc[t - d];
        __syncthreads();
        if (t >= d) sc[t] += v;
        __syncthreads();
    }
    if (i < N_NODES) {
        int excl = sc[t] - c + bbase[blockIdx.x];
        off[i] = excl;
        cursor[i] = excl;
        dinv[i] = 1.0f / sqrtf((float)(c + 1));
    }
}

__global__ void k_fill(const int* __restrict__ row, const int* __restrict__ col,
                       const float* __restrict__ dinv, int* __restrict__ cursor,
                       int2* __restrict__ epack) {
    int e = blockIdx.x * blockDim.x + threadIdx.x;
    if (e >= N_EDGES) return;
    int v = col[e];
    int p = atomicAdd(&cursor[v], 1);
    int r = row[e];
    epack[p] = make_int2(r, __float_as_int(dinv[r]));
}

// W [K][N] fp32 -> transposed split bf16 WT{h,l} [N][K] (weights stay exact)
__global__ void k_prepW(const float* __restrict__ W,
                        unsigned short* __restrict__ Th,
                        unsigned short* __restrict__ Tl, int K, int N) {
    int idx = blockIdx.x * blockDim.x + threadIdx.x;
    if (idx >= K * N) return;
    int n = idx / K, k = idx - n * K;
    float v = W[(size_t)k * N + n];
    unsigned short h = f2bf(v);
    Th[idx] = h;
    Tl[idx] = f2bf(v - bf2f(h));
}

// x fp32 -> bf16, feature-sliced layout: xs[slice=k/16][node][k%16]
__global__ void k_prepX(const float* __restrict__ x, unsigned short* __restrict__ xs) {
    int i = blockIdx.x * blockDim.x + threadIdx.x;
    if (i >= N_NODES * 128) return;
    int v = i >> 7, k = i & 127;
    int sl = k >> 4, w = k & 15;
    xs[(size_t)sl * N_NODES * 16 + (size_t)v * 16 + w] = f2bf(x[i]);
}

// ---------------------------------------------------------------------------
// XCD-affine sliced aggregation:
//   res[v] = dinv[v] * ( x[v]*dinv[v] + sum_j x[r_j]*dinv[r_j] )
// Source is feature-sliced xs[8][N_NODES][DIM/8]; block handles slice
// blockIdx%8 so (with round-robin block->XCD dispatch) each XCD gathers only
// from its own (DIM/8)*N_NODES*2B slice (3.2MB @ DIM=256) -> L2-resident.
// POOL=0: row-major bf16 dest. POOL=1: bias+relu+bucketed mean-pool.
template <int DIM, int POOL>
__global__ __launch_bounds__(256) void k_aggs(
    const unsigned short* __restrict__ xs, const int* __restrict__ off,
    const int2* __restrict__ epack, const float* __restrict__ dinv,
    const float* __restrict__ bias, unsigned short* __restrict__ outb,
    float* __restrict__ gb) {
    const int SW = DIM / 8;       // slice width (32 or 16 elems)
    const int LPN = SW / 8;       // lanes per node-slice (4 or 2)
    const int NPB = 256 / LPN;    // nodes per block (64 or 128)
    __shared__ float gpart[256];
    if (POOL) {
        gpart[threadIdx.x] = 0.0f;
        __syncthreads();
    }
    int sl = blockIdx.x & 7;
    int chunk = blockIdx.x >> 3;
    int v = chunk * NPB + threadIdx.x / LPN;
    int li = threadIdx.x % LPN;
    const unsigned short* __restrict__ xsl =
        xs + (size_t)sl * N_NODES * SW + li * 8;
    float acc[8];
#pragma unroll
    for (int i = 0; i < 8; ++i) acc[i] = 0.f;
    float dv = 0.f;
    if (v < N_NODES) {
        dv = dinv[v];
        uint4 sv = *(const uint4*)&xsl[(size_t)v * SW];
        accum8(acc, sv, dv);
        int s0 = off[v], e0 = off[v + 1];
        int j = s0;
        for (; j + 4 <= e0; j += 4) {
            int2 p0 = epack[j + 0];
            int2 p1 = epack[j + 1];
            int2 p2 = epack[j + 2];
            int2 p3 = epack[j + 3];
            uint4 g0 = *(const uint4*)&xsl[(size_t)p0.x * SW];
            uint4 g1 = *(const uint4*)&xsl[(size_t)p1.x * SW];
            uint4 g2 = *(const uint4*)&xsl[(size_t)p2.x * SW];
            uint4 g3 = *(const uint4*)&xsl[(size_t)p3.x * SW];
            accum8(acc, g0, __int_as_float(p0.y));
            accum8(acc, g1, __int_as_float(p1.y));
            accum8(acc, g2, __int_as_float(p2.y));
            accum8(acc, g3, __int_as_float(p3.y));
        }
        for (; j < e0; ++j) {
            int2 p = epack[j];
            uint4 g = *(const uint4*)&xsl[(size_t)p.x * SW];
            accum8(acc, g, __int_as_float(p.y));
        }
    }
    int fg = sl * SW + li * 8;    // global feature base
    if (!POOL) {
        if (v < N_NODES) {
            uint4 o;
            o.x = (unsigned)f2bf(acc[0] * dv) | ((unsigned)f2bf(acc[1] * dv) << 16);
            o.y = (unsigned)f2bf(acc[2] * dv) | ((unsigned)f2bf(acc[3] * dv) << 16);
            o.z = (unsigned)f2bf(acc[4] * dv) | ((unsigned)f2bf(acc[5] * dv) << 16);
            o.w = (unsigned)f2bf(acc[6] * dv) | ((unsigned)f2bf(acc[7] * dv) << 16);
            *(uint4*)&outb[(size_t)v * DIM + fg] = o;
        }
    } else {
#pragma unroll
        for (int i = 0; i < 8; ++i) {
            float r = (v < N_NODES) ? fmaxf(acc[i] * dv + bias[fg + i], 0.f) : 0.f;
            atomicAdd(&gpart[fg + i], r);
        }
        __syncthreads();
        atomicAdd(&gb[(blockIdx.x & (N_BUCKETS - 1)) * 256 + threadIdx.x],
                  gpart[threadIdx.x]);
    }
}

// ---------------------------------------------------------------------------
// bf16-A x split-bf16-B MFMA GEMM: C[M,N] = A[M,K] @ (Bh+Bl)[K,N] (+bias)(relu)
// B pre-transposed [N][K]. 128x128 tile, BK=32, double-buffered LDS.
// SLICED=1: store C feature-sliced (slice=colg/32) for the agg gather path.
template <int BIAS, int RELU, int SLICED>
__global__ __launch_bounds__(256) void k_gemm_b(
    const unsigned short* __restrict__ A,
    const unsigned short* __restrict__ Bh, const unsigned short* __restrict__ Bl,
    const float* __restrict__ bias, unsigned short* __restrict__ C,
    int M, int K, int N) {
    __shared__ unsigned short As[2][128 * 32];
    __shared__ unsigned short BsH[2][128 * 32];
    __shared__ unsigned short BsL[2][128 * 32];
    int tid = threadIdx.x;
    int lane = tid & 63;
    int w = tid >> 6;
    int wr = w & 1, wc = w >> 1;
    int bm = blockIdx.x * 128, bn = blockIdx.y * 128;

    floatx4 acc[4][4];
    floatx4 zero = {0.f, 0.f, 0.f, 0.f};
#pragma unroll
    for (int t = 0; t < 4; ++t)
#pragma unroll
        for (int u = 0; u < 4; ++u) acc[t][u] = zero;

    int c0 = w * 2, c1 = c0 + 1;
    int srow = lane >> 2;
    int kg = ((lane & 3) - ((lane >> 3) & 3)) & 3;  // global k-chunk (inverse swizzle)
    int kc = kg * 8;
    const unsigned short* Ap0 = A + (size_t)(bm + c0 * 16 + srow) * K + kc;
    const unsigned short* Ap1 = A + (size_t)(bm + c1 * 16 + srow) * K + kc;
    const unsigned short* Bh0 = Bh + (size_t)(bn + c0 * 16 + srow) * K + kc;
    const unsigned short* Bh1 = Bh + (size_t)(bn + c1 * 16 + srow) * K + kc;
    const unsigned short* Bl0 = Bl + (size_t)(bn + c0 * 16 + srow) * K + kc;
    const unsigned short* Bl1 = Bl + (size_t)(bn + c1 * 16 + srow) * K + kc;

    const int KT = K >> 5;
#define STAGE(half, k0)                                   \
    do {                                                  \
        gload16(Ap0 + (k0), &As[half][c0 * 512]);         \
        gload16(Ap1 + (k0), &As[half][c1 * 512]);         \
        gload16(Bh0 + (k0), &BsH[half][c0 * 512]);        \
        gload16(Bh1 + (k0), &BsH[half][c1 * 512]);        \
        gload16(Bl0 + (k0), &BsL[half][c0 * 512]);        \
        gload16(Bl1 + (k0), &BsL[half][c1 * 512]);        \
    } while (0)

    STAGE(0, 0);
    __syncthreads();

    int fr = lane & 15;            // m (A) / n (B) within 16-tile
    int fq = lane >> 4;            // k-chunk 0..3
    int cl = ((fq + (fr >> 1)) & 3) * 8;  // swizzled LDS k-chunk offset

    for (int kt = 0; kt < KT; ++kt) {
        int half = kt & 1;
        if (kt + 1 < KT) STAGE(1 - half, (kt + 1) * 32);
        short8 av[4], bhv[4], blv[4];
#pragma unroll
        for (int t = 0; t < 4; ++t) {
            av[t]  = *(const short8*)&As[half][(wr * 64 + t * 16 + fr) * 32 + cl];
            bhv[t] = *(const short8*)&BsH[half][(wc * 64 + t * 16 + fr) * 32 + cl];
            blv[t] = *(const short8*)&BsL[half][(wc * 64 + t * 16 + fr) * 32 + cl];
        }
#pragma unroll
        for (int t = 0; t < 4; ++t)
#pragma unroll
            for (int u = 0; u < 4; ++u) {
                acc[t][u] = __builtin_amdgcn_mfma_f32_16x16x32_bf16(av[t], bhv[u], acc[t][u], 0, 0, 0);
                acc[t][u] = __builtin_amdgcn_mfma_f32_16x16x32_bf16(av[t], blv[u], acc[t][u], 0, 0, 0);
            }
        __syncthreads();
    }
#undef STAGE

    // epilogue: C/D layout col = lane&15, row = (lane>>4)*4 + reg
#pragma unroll
    for (int u = 0; u < 4; ++u) {
        int colg = bn + wc * 64 + u * 16 + fr;
        float bv = BIAS ? bias[colg] : 0.0f;
#pragma unroll
        for (int t = 0; t < 4; ++t) {
#pragma unroll
            for (int r = 0; r < 4; ++r) {
                int rowg = bm + wr * 64 + t * 16 + fq * 4 + r;
                if (rowg < M) {
                    float o = acc[t][u][r] + bv;
                    if (RELU) o = fmaxf(o, 0.f);
                    if (SLICED) {
                        // sliced store: [slice=colg/32][row][colg%32]
                        C[(size_t)(colg >> 5) * N_NODES * 32 +
                          (size_t)rowg * 32 + (colg & 31)] = f2bf(o);
                    } else {
                        C[(size_t)rowg * N + colg] = f2bf(o);
                    }
                }
            }
        }
    }
}

// tiny MLP; first reduces the 64 pool buckets
__global__ void k_mlp(const float* __restrict__ gb,
                      const float* __restrict__ Wf1, const float* __restrict__ bf1,
                      const float* __restrict__ Wf2, const float* __restrict__ bf2,
                      const float* __restrict__ Wf3, const float* __restrict__ bf3,
                      float* __restrict__ out) {
    __shared__ float s0[256], s1[128], s2[64];
    int t = threadIdx.x;
    float sum = 0.0f;
    for (int b = 0; b < N_BUCKETS; ++b) sum += gb[b * 256 + t];
    s0[t] = sum * (1.0f / (float)N_NODES);
    __syncthreads();
    if (t < 128) {
        float a = bf1[t];
        for (int k = 0; k < 256; ++k) a += s0[k] * Wf1[k * 128 + t];
        s1[t] = fmaxf(a, 0.0f);
    }
    __syncthreads();
    if (t < 64) {
        float a = bf2[t];
        for (int k = 0; k < 128; ++k) a += s1[k] * Wf2[k * 64 + t];
        s2[t] = fmaxf(a, 0.0f);
    }
    __syncthreads();
    if (t == 0) {
        float a = bf3[0];
        for (int k = 0; k < 64; ++k) a += s2[k] * Wf3[k];
        out[0] = a;
    }
}

extern "C" void kernel_launch(void* const* d_in, const int* in_sizes, int n_in,
                              void* d_out, int out_size, void* d_ws, size_t ws_size,
                              hipStream_t stream) {
    const float* x  = (const float*)d_in[0];
    const int* ei   = (const int*)d_in[1];
    const float* W1 = (const float*)d_in[2];
    const float* b1 = (const float*)d_in[3];
    const float* W2 = (const float*)d_in[4];
    const float* b2 = (const float*)d_in[5];
    const float* W3 = (const float*)d_in[6];
    const float* b3 = (const float*)d_in[7];
    const float* Wf1 = (const float*)d_in[8];
    const float* bf1 = (const float*)d_in[9];
    const float* Wf2 = (const float*)d_in[10];
    const float* bf2 = (const float*)d_in[11];
    const float* Wf3 = (const float*)d_in[12];
    const float* bf3 = (const float*)d_in[13];
    float* out = (float*)d_out;

    char* p = (char*)d_ws;
    auto alloc = [&](size_t bytes) {
        void* r = (void*)p;
        p += (bytes + 255) & ~((size_t)255);
        return r;
    };
    int*   cnt    = (int*)  alloc(N_NODES * sizeof(int));
    int*   off    = (int*)  alloc((N_NODES + 1) * sizeof(int));
    int*   cursor = (int*)  alloc(N_NODES * sizeof(int));
    int*   bsum   = (int*)  alloc(SCAN_NB * sizeof(int));
    int*   bbase  = (int*)  alloc(SCAN_NB * sizeof(int));
    float* dinv   = (float*)alloc(N_NODES * sizeof(float));
    int2*  epack  = (int2*) alloc((size_t)N_EDGES * sizeof(int2));
    float* gb     = (float*)alloc(N_BUCKETS * 256 * sizeof(float));
    unsigned short* W1h = (unsigned short*)alloc(128 * 256 * 2);
    unsigned short* W1l = (unsigned short*)alloc(128 * 256 * 2);
    unsigned short* W2h = (unsigned short*)alloc(256 * 512 * 2);
    unsigned short* W2l = (unsigned short*)alloc(256 * 512 * 2);
    unsigned short* W3h = (unsigned short*)alloc(512 * 256 * 2);
    unsigned short* W3l = (unsigned short*)alloc(512 * 256 * 2);
    unsigned short* xbs = (unsigned short*)alloc((size_t)N_NODES * 128 * 2);  // sliced
    unsigned short* t0  = (unsigned short*)alloc((size_t)M_PAD * 128 * 2);    // row-major
    unsigned short* h1s = (unsigned short*)alloc((size_t)N_NODES * 256 * 2);  // sliced
    unsigned short* t1  = (unsigned short*)alloc((size_t)M_PAD * 256 * 2);    // row-major
    unsigned short* h2  = (unsigned short*)alloc((size_t)M_PAD * 512 * 2);    // row-major
    unsigned short* t2s = (unsigned short*)alloc((size_t)N_NODES * 256 * 2);  // sliced

    const int* row = ei;
    const int* col = ei + N_EDGES;

    const int NB = (N_NODES + 255) / 256;  // 196
    const int EB = (N_EDGES + 255) / 256;

    // CSR build + norm (hierarchical scan)
    k_init<<<NB, 256, 0, stream>>>(cnt, gb);
    k_count<<<EB, 256, 0, stream>>>(col, cnt);
    k_scanA<<<SCAN_NB, 256, 0, stream>>>(cnt, bsum);
    k_scanB<<<1, 256, 0, stream>>>(bsum, bbase, off);
    k_scanC<<<SCAN_NB, 256, 0, stream>>>(cnt, bbase, off, cursor, dinv);
    k_fill<<<EB, 256, 0, stream>>>(row, col, dinv, cursor, epack);

    // weight prep (transpose + exact split) and x -> sliced bf16
    k_prepW<<<(128 * 256 + 255) / 256, 256, 0, stream>>>(W1, W1h, W1l, 128, 256);
    k_prepW<<<(256 * 512 + 255) / 256, 256, 0, stream>>>(W2, W2h, W2l, 256, 512);
    k_prepW<<<(512 * 256 + 255) / 256, 256, 0, stream>>>(W3, W3h, W3l, 512, 256);
    k_prepX<<<(N_NODES * 128 + 255) / 256, 256, 0, stream>>>(x, xbs);

    const int M = N_NODES;
    const int MB = (M + 127) / 128; // 391

    // conv1: t0 = agg(x, sliced); h1 = relu(t0@W1 + b1) -> sliced
    k_aggs<128, 0><<<8 * ((N_NODES + 127) / 128), 256, 0, stream>>>(
        xbs, off, epack, dinv, nullptr, t0, nullptr);
    {
        dim3 grid(MB, 256 / 128);
        k_gemm_b<1, 1, 1><<<grid, 256, 0, stream>>>(t0, W1h, W1l, b1, h1s, M, 128, 256);
    }
    // conv2: t1 = agg(h1, sliced); h2 = relu(t1@W2 + b2) row-major
    k_aggs<256, 0><<<8 * ((N_NODES + 63) / 64), 256, 0, stream>>>(
        h1s, off, epack, dinv, nullptr, t1, nullptr);
    {
        dim3 grid(MB, 512 / 128);
        k_gemm_b<1, 1, 0><<<grid, 256, 0, stream>>>(t1, W2h, W2l, b2, h2, M, 256, 512);
    }
    // conv3: t2 = h2@W3 -> sliced; fused agg + bias + relu + bucketed mean-pool
    {
        dim3 grid(MB, 256 / 128);
        k_gemm_b<0, 0, 1><<<grid, 256, 0, stream>>>(h2, W3h, W3l, nullptr, t2s, M, 512, 256);
    }
    k_aggs<256, 1><<<8 * ((N_NODES + 63) / 64), 256, 0, stream>>>(
        t2s, off, epack, dinv, b3, nullptr, gb);

    // MLP (reduces buckets internally)
    k_mlp<<<1, 256, 0, stream>>>(gb, Wf1, bf1, Wf2, bf2, Wf3, bf3, out);
}

// Round 10
// 531.091 us; speedup vs baseline: 1.0294x; 1.0286x over previous
//
#include <hip/hip_runtime.h>
#include <hip/hip_bf16.h>

#define N_NODES 50000
#define N_EDGES 800000
#define N_BUCKETS 64
#define M_PAD 50048  // 391 * 128, pads GEMM A-inputs so staging never reads OOB
#define SCAN_NB 196  // ceil(50000 / 256)

typedef short short8 __attribute__((ext_vector_type(8)));
typedef float floatx4 __attribute__((ext_vector_type(4)));

// ---- bf16 helpers (RNE) ---------------------------------------------------
__device__ __forceinline__ unsigned short f2bf(float f) {
    unsigned u = __float_as_uint(f);
    unsigned r = (u + 0x7fff + ((u >> 16) & 1)) >> 16;
    return (unsigned short)r;
}
__device__ __forceinline__ float bf2f(unsigned short h) {
    return __uint_as_float(((unsigned)h) << 16);
}
__device__ __forceinline__ void expand2(unsigned u, float& lo, float& hi) {
    lo = __uint_as_float(u << 16);
    hi = __uint_as_float(u & 0xffff0000u);
}
// 4 features from one uint2 (4 bf16)
__device__ __forceinline__ void accum4(float* a, uint2 g, float w) {
    float lo, hi;
    expand2(g.x, lo, hi); a[0] += lo * w; a[1] += hi * w;
    expand2(g.y, lo, hi); a[2] += lo * w; a[3] += hi * w;
}
// 2 features from one uint (2 bf16)
__device__ __forceinline__ void accum2(float* a, unsigned g, float w) {
    float lo, hi;
    expand2(g, lo, hi); a[0] += lo * w; a[1] += hi * w;
}

// async global->LDS, 16B per lane; lds dest = wave-uniform base + lane*16
__device__ __forceinline__ void gload16(const void* gp, void* lp) {
    __builtin_amdgcn_global_load_lds(
        (const __attribute__((address_space(1))) unsigned int*)gp,
        (__attribute__((address_space(3))) unsigned int*)lp,
        16, 0, 0);
}

// ---------------------------------------------------------------------------
__global__ void k_init(int* __restrict__ cnt, float* __restrict__ gb) {
    int i = blockIdx.x * blockDim.x + threadIdx.x;
    if (i < N_NODES) cnt[i] = 0;
    if (i < N_BUCKETS * 256) gb[i] = 0.0f;
}

__global__ void k_count(const int* __restrict__ col, int* __restrict__ cnt) {
    int e = blockIdx.x * blockDim.x + threadIdx.x;
    if (e < N_EDGES) atomicAdd(&cnt[col[e]], 1);
}

// --- 3-phase hierarchical exclusive scan of cnt -> off/cursor --------------
__global__ __launch_bounds__(256) void k_scanA(const int* __restrict__ cnt,
                                               int* __restrict__ bsum) {
    __shared__ int red[256];
    int t = threadIdx.x;
    int i = blockIdx.x * 256 + t;
    red[t] = (i < N_NODES) ? cnt[i] : 0;
    __syncthreads();
    for (int d = 128; d > 0; d >>= 1) {
        if (t < d) red[t] += red[t + d];
        __syncthreads();
    }
    if (t == 0) bsum[blockIdx.x] = red[0];
}

__global__ __launch_bounds__(256) void k_scanB(const int* __restrict__ bsum,
                                               int* __restrict__ bbase,
                                               int* __restrict__ off) {
    __shared__ int sc[256];
    int t = threadIdx.x;
    sc[t] = (t < SCAN_NB) ? bsum[t] : 0;
    __syncthreads();
    for (int d = 1; d < 256; d <<= 1) {
        int v = 0;
        if (t >= d) v = sc[t - d];
        __syncthreads();
        if (t >= d) sc[t] += v;
        __syncthreads();
    }
    if (t < SCAN_NB) bbase[t] = sc[t] - bsum[t];  // exclusive
    if (t == 0) off[N_NODES] = N_EDGES;
}

__global__ __launch_bounds__(256) void k_scanC(const int* __restrict__ cnt,
                                               const int* __restrict__ bbase,
                                               int* __restrict__ off,
                                               int* __restrict__ cursor,
                                               float* __restrict__ dinv) {
    __shared__ int sc[256];
    int t = threadIdx.x;
    int i = blockIdx.x * 256 + t;
    int c = (i < N_NODES) ? cnt[i] : 0;
    sc[t] = c;
    __syncthreads();
    for (int d = 1; d < 256; d <<= 1) {
        int v = 0;
        if (t >= d) v = sc[t - d];
        __syncthreads();
        if (t >= d) sc[t] += v;
        __syncthreads();
    }
    if (i < N_NODES) {
        int excl = sc[t] - c + bbase[blockIdx.x];
        off[i] = excl;
        cursor[i] = excl;
        dinv[i] = 1.0f / sqrtf((float)(c + 1));
    }
}

__global__ void k_fill(const int* __restrict__ row, const int* __restrict__ col,
                       const float* __restrict__ dinv, int* __restrict__ cursor,
                       int2* __restrict__ epack) {
    int e = blockIdx.x * blockDim.x + threadIdx.x;
    if (e >= N_EDGES) return;
    int v = col[e];
    int p = atomicAdd(&cursor[v], 1);
    int r = row[e];
    epack[p] = make_int2(r, __float_as_int(dinv[r]));
}

// W [K][N] fp32 -> transposed split bf16 WT{h,l} [N][K] (weights stay exact)
__global__ void k_prepW(const float* __restrict__ W,
                        unsigned short* __restrict__ Th,
                        unsigned short* __restrict__ Tl, int K, int N) {
    int idx = blockIdx.x * blockDim.x + threadIdx.x;
    if (idx >= K * N) return;
    int n = idx / K, k = idx - n * K;
    float v = W[(size_t)k * N + n];
    unsigned short h = f2bf(v);
    Th[idx] = h;
    Tl[idx] = f2bf(v - bf2f(h));
}

// x fp32 -> bf16 (row-major)
__global__ void k_prepX(const float* __restrict__ x, unsigned short* __restrict__ xb) {
    int i = blockIdx.x * blockDim.x + threadIdx.x;
    if (i < N_NODES * 128) xb[i] = f2bf(x[i]);
}

// ---------------------------------------------------------------------------
// Wave-per-node aggregation (one full wave owns one node):
//   res[v] = dinv[v] * ( x[v]*dinv[v] + sum_j x[r_j]*dinv[r_j] )
// Every gather is ONE contiguous 512B (DIM=256) / 256B (DIM=128) segment per
// wave-instruction — the coalescer fast path (R3 evidence: 7.1 TB/s vs 3.9
// for multi-node waves). No inter-node lockstep divergence.
// POOL=0: row-major bf16 out. POOL=1: bias+relu+bucketed mean-pool.
template <int DIM, int POOL>
__global__ __launch_bounds__(256) void k_aggw(
    const unsigned short* __restrict__ xb, const int* __restrict__ off,
    const int2* __restrict__ epack, const float* __restrict__ dinv,
    const float* __restrict__ bias, unsigned short* __restrict__ outb,
    float* __restrict__ gb) {
    const int EPL = DIM / 64;     // features per lane: 4 (256) or 2 (128)
    __shared__ float gpart[256];
    if (POOL) {
        gpart[threadIdx.x] = 0.0f;
        __syncthreads();
    }
    int wv = threadIdx.x >> 6;        // wave within block (0..3)
    int li = threadIdx.x & 63;        // lane
    int v = blockIdx.x * 4 + wv;      // node (grid divides N exactly)
    int f = li * EPL;
    float dv = dinv[v];
    const unsigned short* __restrict__ xf = xb + f;
    float a0[EPL], a1[EPL], a2[EPL], a3[EPL];
#pragma unroll
    for (int i = 0; i < EPL; ++i) { a0[i] = 0.f; a1[i] = 0.f; a2[i] = 0.f; a3[i] = 0.f; }
    if (EPL == 4) {
        uint2 sv = *(const uint2*)&xf[(size_t)v * DIM];
        accum4(a0, sv, dv);
    } else {
        unsigned sv = *(const unsigned*)&xf[(size_t)v * DIM];
        accum2(a0, sv, dv);
    }
    int s = off[v], e = off[v + 1];
    int j = s;
    for (; j + 4 <= e; j += 4) {
        int2 p0 = epack[j + 0];
        int2 p1 = epack[j + 1];
        int2 p2 = epack[j + 2];
        int2 p3 = epack[j + 3];
        if (EPL == 4) {
            uint2 g0 = *(const uint2*)&xf[(size_t)p0.x * DIM];
            uint2 g1 = *(const uint2*)&xf[(size_t)p1.x * DIM];
            uint2 g2 = *(const uint2*)&xf[(size_t)p2.x * DIM];
            uint2 g3 = *(const uint2*)&xf[(size_t)p3.x * DIM];
            accum4(a0, g0, __int_as_float(p0.y));
            accum4(a1, g1, __int_as_float(p1.y));
            accum4(a2, g2, __int_as_float(p2.y));
            accum4(a3, g3, __int_as_float(p3.y));
        } else {
            unsigned g0 = *(const unsigned*)&xf[(size_t)p0.x * DIM];
            unsigned g1 = *(const unsigned*)&xf[(size_t)p1.x * DIM];
            unsigned g2 = *(const unsigned*)&xf[(size_t)p2.x * DIM];
            unsigned g3 = *(const unsigned*)&xf[(size_t)p3.x * DIM];
            accum2(a0, g0, __int_as_float(p0.y));
            accum2(a1, g1, __int_as_float(p1.y));
            accum2(a2, g2, __int_as_float(p2.y));
            accum2(a3, g3, __int_as_float(p3.y));
        }
    }
    for (; j < e; ++j) {
        int2 p = epack[j];
        if (EPL == 4) {
            uint2 g = *(const uint2*)&xf[(size_t)p.x * DIM];
            accum4(a0, g, __int_as_float(p.y));
        } else {
            unsigned g = *(const unsigned*)&xf[(size_t)p.x * DIM];
            accum2(a0, g, __int_as_float(p.y));
        }
    }
    float acc[EPL];
#pragma unroll
    for (int i = 0; i < EPL; ++i)
        acc[i] = ((a0[i] + a1[i]) + (a2[i] + a3[i])) * dv;
    if (!POOL) {
        if (EPL == 4) {
            uint2 o;
            o.x = (unsigned)f2bf(acc[0]) | ((unsigned)f2bf(acc[1]) << 16);
            o.y = (unsigned)f2bf(acc[2]) | ((unsigned)f2bf(acc[3]) << 16);
            *(uint2*)&outb[(size_t)v * DIM + f] = o;
        } else {
            unsigned o = (unsigned)f2bf(acc[0]) | ((unsigned)f2bf(acc[1]) << 16);
            *(unsigned*)&outb[(size_t)v * DIM + f] = o;
        }
    } else {
#pragma unroll
        for (int i = 0; i < EPL; ++i) {
            float r = fmaxf(acc[i] + bias[f + i], 0.0f);
            atomicAdd(&gpart[f + i], r);
        }
        __syncthreads();
        atomicAdd(&gb[(blockIdx.x & (N_BUCKETS - 1)) * 256 + threadIdx.x],
                  gpart[threadIdx.x]);
    }
}

// ---------------------------------------------------------------------------
// bf16-A x split-bf16-B MFMA GEMM: C[M,N] = A[M,K] @ (Bh+Bl)[K,N] (+bias)(relu)
// B pre-transposed [N][K]. 128x128 tile, BK=32, double-buffered LDS.
// LDS k-chunks swizzled by (row>>1)&3 to break the 64B-row-stride conflicts.
template <int BIAS, int RELU>
__global__ __launch_bounds__(256) void k_gemm_b(
    const unsigned short* __restrict__ A,
    const unsigned short* __restrict__ Bh, const unsigned short* __restrict__ Bl,
    const float* __restrict__ bias, unsigned short* __restrict__ C,
    int M, int K, int N) {
    __shared__ unsigned short As[2][128 * 32];
    __shared__ unsigned short BsH[2][128 * 32];
    __shared__ unsigned short BsL[2][128 * 32];
    int tid = threadIdx.x;
    int lane = tid & 63;
    int w = tid >> 6;
    int wr = w & 1, wc = w >> 1;
    int bm = blockIdx.x * 128, bn = blockIdx.y * 128;

    floatx4 acc[4][4];
    floatx4 zero = {0.f, 0.f, 0.f, 0.f};
#pragma unroll
    for (int t = 0; t < 4; ++t)
#pragma unroll
        for (int u = 0; u < 4; ++u) acc[t][u] = zero;

    int c0 = w * 2, c1 = c0 + 1;
    int srow = lane >> 2;
    int kg = ((lane & 3) - ((lane >> 3) & 3)) & 3;  // global k-chunk (inverse swizzle)
    int kc = kg * 8;
    const unsigned short* Ap0 = A + (size_t)(bm + c0 * 16 + srow) * K + kc;
    const unsigned short* Ap1 = A + (size_t)(bm + c1 * 16 + srow) * K + kc;
    const unsigned short* Bh0 = Bh + (size_t)(bn + c0 * 16 + srow) * K + kc;
    const unsigned short* Bh1 = Bh + (size_t)(bn + c1 * 16 + srow) * K + kc;
    const unsigned short* Bl0 = Bl + (size_t)(bn + c0 * 16 + srow) * K + kc;
    const unsigned short* Bl1 = Bl + (size_t)(bn + c1 * 16 + srow) * K + kc;

    const int KT = K >> 5;
#define STAGE(half, k0)                                   \
    do {                                                  \
        gload16(Ap0 + (k0), &As[half][c0 * 512]);         \
        gload16(Ap1 + (k0), &As[half][c1 * 512]);         \
        gload16(Bh0 + (k0), &BsH[half][c0 * 512]);        \
        gload16(Bh1 + (k0), &BsH[half][c1 * 512]);        \
        gload16(Bl0 + (k0), &BsL[half][c0 * 512]);        \
        gload16(Bl1 + (k0), &BsL[half][c1 * 512]);        \
    } while (0)

    STAGE(0, 0);
    __syncthreads();

    int fr = lane & 15;            // m (A) / n (B) within 16-tile
    int fq = lane >> 4;            // k-chunk 0..3
    int cl = ((fq + (fr >> 1)) & 3) * 8;  // swizzled LDS k-chunk offset

    for (int kt = 0; kt < KT; ++kt) {
        int half = kt & 1;
        if (kt + 1 < KT) STAGE(1 - half, (kt + 1) * 32);
        short8 av[4], bhv[4], blv[4];
#pragma unroll
        for (int t = 0; t < 4; ++t) {
            av[t]  = *(const short8*)&As[half][(wr * 64 + t * 16 + fr) * 32 + cl];
            bhv[t] = *(const short8*)&BsH[half][(wc * 64 + t * 16 + fr) * 32 + cl];
            blv[t] = *(const short8*)&BsL[half][(wc * 64 + t * 16 + fr) * 32 + cl];
        }
#pragma unroll
        for (int t = 0; t < 4; ++t)
#pragma unroll
            for (int u = 0; u < 4; ++u) {
                acc[t][u] = __builtin_amdgcn_mfma_f32_16x16x32_bf16(av[t], bhv[u], acc[t][u], 0, 0, 0);
                acc[t][u] = __builtin_amdgcn_mfma_f32_16x16x32_bf16(av[t], blv[u], acc[t][u], 0, 0, 0);
            }
        __syncthreads();
    }
#undef STAGE

    // epilogue: C/D layout col = lane&15, row = (lane>>4)*4 + reg
#pragma unroll
    for (int u = 0; u < 4; ++u) {
        int colg = bn + wc * 64 + u * 16 + fr;
        float bv = BIAS ? bias[colg] : 0.0f;
#pragma unroll
        for (int t = 0; t < 4; ++t) {
#pragma unroll
            for (int r = 0; r < 4; ++r) {
                int rowg = bm + wr * 64 + t * 16 + fq * 4 + r;
                if (rowg < M) {
                    float o = acc[t][u][r] + bv;
                    if (RELU) o = fmaxf(o, 0.f);
                    C[(size_t)rowg * N + colg] = f2bf(o);
                }
            }
        }
    }
}

// tiny MLP; first reduces the 64 pool buckets
__global__ void k_mlp(const float* __restrict__ gb,
                      const float* __restrict__ Wf1, const float* __restrict__ bf1,
                      const float* __restrict__ Wf2, const float* __restrict__ bf2,
                      const float* __restrict__ Wf3, const float* __restrict__ bf3,
                      float* __restrict__ out) {
    __shared__ float s0[256], s1[128], s2[64];
    int t = threadIdx.x;
    float sum = 0.0f;
    for (int b = 0; b < N_BUCKETS; ++b) sum += gb[b * 256 + t];
    s0[t] = sum * (1.0f / (float)N_NODES);
    __syncthreads();
    if (t < 128) {
        float a = bf1[t];
        for (int k = 0; k < 256; ++k) a += s0[k] * Wf1[k * 128 + t];
        s1[t] = fmaxf(a, 0.0f);
    }
    __syncthreads();
    if (t < 64) {
        float a = bf2[t];
        for (int k = 0; k < 128; ++k) a += s1[k] * Wf2[k * 64 + t];
        s2[t] = fmaxf(a, 0.0f);
    }
    __syncthreads();
    if (t == 0) {
        float a = bf3[0];
        for (int k = 0; k < 64; ++k) a += s2[k] * Wf3[k];
        out[0] = a;
    }
}

extern "C" void kernel_launch(void* const* d_in, const int* in_sizes, int n_in,
                              void* d_out, int out_size, void* d_ws, size_t ws_size,
                              hipStream_t stream) {
    const float* x  = (const float*)d_in[0];
    const int* ei   = (const int*)d_in[1];
    const float* W1 = (const float*)d_in[2];
    const float* b1 = (const float*)d_in[3];
    const float* W2 = (const float*)d_in[4];
    const float* b2 = (const float*)d_in[5];
    const float* W3 = (const float*)d_in[6];
    const float* b3 = (const float*)d_in[7];
    const float* Wf1 = (const float*)d_in[8];
    const float* bf1 = (const float*)d_in[9];
    const float* Wf2 = (const float*)d_in[10];
    const float* bf2 = (const float*)d_in[11];
    const float* Wf3 = (const float*)d_in[12];
    const float* bf3 = (const float*)d_in[13];
    float* out = (float*)d_out;

    char* p = (char*)d_ws;
    auto alloc = [&](size_t bytes) {
        void* r = (void*)p;
        p += (bytes + 255) & ~((size_t)255);
        return r;
    };
    int*   cnt    = (int*)  alloc(N_NODES * sizeof(int));
    int*   off    = (int*)  alloc((N_NODES + 1) * sizeof(int));
    int*   cursor = (int*)  alloc(N_NODES * sizeof(int));
    int*   bsum   = (int*)  alloc(SCAN_NB * sizeof(int));
    int*   bbase  = (int*)  alloc(SCAN_NB * sizeof(int));
    float* dinv   = (float*)alloc(N_NODES * sizeof(float));
    int2*  epack  = (int2*) alloc((size_t)N_EDGES * sizeof(int2));
    float* gb     = (float*)alloc(N_BUCKETS * 256 * sizeof(float));
    unsigned short* W1h = (unsigned short*)alloc(128 * 256 * 2);
    unsigned short* W1l = (unsigned short*)alloc(128 * 256 * 2);
    unsigned short* W2h = (unsigned short*)alloc(256 * 512 * 2);
    unsigned short* W2l = (unsigned short*)alloc(256 * 512 * 2);
    unsigned short* W3h = (unsigned short*)alloc(512 * 256 * 2);
    unsigned short* W3l = (unsigned short*)alloc(512 * 256 * 2);
    unsigned short* xb = (unsigned short*)alloc((size_t)N_NODES * 128 * 2);
    unsigned short* t0 = (unsigned short*)alloc((size_t)M_PAD * 128 * 2);
    unsigned short* h1 = (unsigned short*)alloc((size_t)N_NODES * 256 * 2);
    unsigned short* t1 = (unsigned short*)alloc((size_t)M_PAD * 256 * 2);
    unsigned short* h2 = (unsigned short*)alloc((size_t)M_PAD * 512 * 2);
    unsigned short* t2 = (unsigned short*)alloc((size_t)N_NODES * 256 * 2);

    const int* row = ei;
    const int* col = ei + N_EDGES;

    const int NB = (N_NODES + 255) / 256;  // 196
    const int EB = (N_EDGES + 255) / 256;

    // CSR build + norm (hierarchical scan)
    k_init<<<NB, 256, 0, stream>>>(cnt, gb);
    k_count<<<EB, 256, 0, stream>>>(col, cnt);
    k_scanA<<<SCAN_NB, 256, 0, stream>>>(cnt, bsum);
    k_scanB<<<1, 256, 0, stream>>>(bsum, bbase, off);
    k_scanC<<<SCAN_NB, 256, 0, stream>>>(cnt, bbase, off, cursor, dinv);
    k_fill<<<EB, 256, 0, stream>>>(row, col, dinv, cursor, epack);

    // weight prep (transpose + exact split) and x -> bf16
    k_prepW<<<(128 * 256 + 255) / 256, 256, 0, stream>>>(W1, W1h, W1l, 128, 256);
    k_prepW<<<(256 * 512 + 255) / 256, 256, 0, stream>>>(W2, W2h, W2l, 256, 512);
    k_prepW<<<(512 * 256 + 255) / 256, 256, 0, stream>>>(W3, W3h, W3l, 512, 256);
    k_prepX<<<(N_NODES * 128 + 255) / 256, 256, 0, stream>>>(x, xb);

    const int M = N_NODES;
    const int MB = (M + 127) / 128; // 391

    // conv1: t0 = agg(xb); h1 = relu(t0@W1 + b1)
    k_aggw<128, 0><<<N_NODES / 4, 256, 0, stream>>>(
        xb, off, epack, dinv, nullptr, t0, nullptr);
    {
        dim3 grid(MB, 256 / 128);
        k_gemm_b<1, 1><<<grid, 256, 0, stream>>>(t0, W1h, W1l, b1, h1, M, 128, 256);
    }
    // conv2: t1 = agg(h1); h2 = relu(t1@W2 + b2)
    k_aggw<256, 0><<<N_NODES / 4, 256, 0, stream>>>(
        h1, off, epack, dinv, nullptr, t1, nullptr);
    {
        dim3 grid(MB, 512 / 128);
        k_gemm_b<1, 1><<<grid, 256, 0, stream>>>(t1, W2h, W2l, b2, h2, M, 256, 512);
    }
    // conv3: t2 = h2@W3; fused agg + bias + relu + bucketed mean-pool
    {
        dim3 grid(MB, 256 / 128);
        k_gemm_b<0, 0><<<grid, 256, 0, stream>>>(h2, W3h, W3l, nullptr, t2, M, 512, 256);
    }
    k_aggw<256, 1><<<N_NODES / 4, 256, 0, stream>>>(
        t2, off, epack, dinv, b3, nullptr, gb);

    // MLP (reduces buckets internally)
    k_mlp<<<1, 256, 0, stream>>>(gb, Wf1, bf1, Wf2, bf2, Wf3, bf3, out);
}

// Round 11
// 529.246 us; speedup vs baseline: 1.0330x; 1.0035x over previous
//
#include <hip/hip_runtime.h>
#include <hip/hip_bf16.h>

#define N_NODES 50000
#define N_EDGES 800000
#define N_BUCKETS 64
#define M_PAD 50048  // 391 * 128, pads GEMM A-inputs so staging never reads OOB
#define SCAN_NB 196  // ceil(50000 / 256)

typedef short short8 __attribute__((ext_vector_type(8)));
typedef float floatx4 __attribute__((ext_vector_type(4)));

// ---- bf16 helpers (RNE) ---------------------------------------------------
__device__ __forceinline__ unsigned short f2bf(float f) {
    unsigned u = __float_as_uint(f);
    unsigned r = (u + 0x7fff + ((u >> 16) & 1)) >> 16;
    return (unsigned short)r;
}
__device__ __forceinline__ float bf2f(unsigned short h) {
    return __uint_as_float(((unsigned)h) << 16);
}
__device__ __forceinline__ void expand2(unsigned u, float& lo, float& hi) {
    lo = __uint_as_float(u << 16);
    hi = __uint_as_float(u & 0xffff0000u);
}
// 8 features from one uint4 (8 bf16)
__device__ __forceinline__ void accum8(float* a, uint4 g, float w) {
    float lo, hi;
    expand2(g.x, lo, hi); a[0] += lo * w; a[1] += hi * w;
    expand2(g.y, lo, hi); a[2] += lo * w; a[3] += hi * w;
    expand2(g.z, lo, hi); a[4] += lo * w; a[5] += hi * w;
    expand2(g.w, lo, hi); a[6] += lo * w; a[7] += hi * w;
}

// async global->LDS, 16B per lane; lds dest = wave-uniform base + lane*16
__device__ __forceinline__ void gload16(const void* gp, void* lp) {
    __builtin_amdgcn_global_load_lds(
        (const __attribute__((address_space(1))) unsigned int*)gp,
        (__attribute__((address_space(3))) unsigned int*)lp,
        16, 0, 0);
}

// ---------------------------------------------------------------------------
__global__ void k_init(int* __restrict__ cnt, float* __restrict__ gb) {
    int i = blockIdx.x * blockDim.x + threadIdx.x;
    if (i < N_NODES) cnt[i] = 0;
    if (i < N_BUCKETS * 256) gb[i] = 0.0f;
}

__global__ void k_count(const int* __restrict__ col, int* __restrict__ cnt) {
    int e = blockIdx.x * blockDim.x + threadIdx.x;
    if (e < N_EDGES) atomicAdd(&cnt[col[e]], 1);
}

// --- 3-phase hierarchical exclusive scan of cnt -> off/cursor --------------
__global__ __launch_bounds__(256) void k_scanA(const int* __restrict__ cnt,
                                               int* __restrict__ bsum) {
    __shared__ int red[256];
    int t = threadIdx.x;
    int i = blockIdx.x * 256 + t;
    red[t] = (i < N_NODES) ? cnt[i] : 0;
    __syncthreads();
    for (int d = 128; d > 0; d >>= 1) {
        if (t < d) red[t] += red[t + d];
        __syncthreads();
    }
    if (t == 0) bsum[blockIdx.x] = red[0];
}

__global__ __launch_bounds__(256) void k_scanB(const int* __restrict__ bsum,
                                               int* __restrict__ bbase,
                                               int* __restrict__ off) {
    __shared__ int sc[256];
    int t = threadIdx.x;
    sc[t] = (t < SCAN_NB) ? bsum[t] : 0;
    __syncthreads();
    for (int d = 1; d < 256; d <<= 1) {
        int v = 0;
        if (t >= d) v = sc[t - d];
        __syncthreads();
        if (t >= d) sc[t] += v;
        __syncthreads();
    }
    if (t < SCAN_NB) bbase[t] = sc[t] - bsum[t];  // exclusive
    if (t == 0) off[N_NODES] = N_EDGES;
}

__global__ __launch_bounds__(256) void k_scanC(const int* __restrict__ cnt,
                                               const int* __restrict__ bbase,
                                               int* __restrict__ off,
                                               int* __restrict__ cursor,
                                               float* __restrict__ dinv) {
    __shared__ int sc[256];
    int t = threadIdx.x;
    int i = blockIdx.x * 256 + t;
    int c = (i < N_NODES) ? cnt[i] : 0;
    sc[t] = c;
    __syncthreads();
    for (int d = 1; d < 256; d <<= 1) {
        int v = 0;
        if (t >= d) v = sc[t - d];
        __syncthreads();
        if (t >= d) sc[t] += v;
        __syncthreads();
    }
    if (i < N_NODES) {
        int excl = sc[t] - c + bbase[blockIdx.x];
        off[i] = excl;
        cursor[i] = excl;
        dinv[i] = 1.0f / sqrtf((float)(c + 1));
    }
}

__global__ void k_fill(const int* __restrict__ row, const int* __restrict__ col,
                       const float* __restrict__ dinv, int* __restrict__ cursor,
                       int2* __restrict__ epack) {
    int e = blockIdx.x * blockDim.x + threadIdx.x;
    if (e >= N_EDGES) return;
    int v = col[e];
    int p = atomicAdd(&cursor[v], 1);
    int r = row[e];
    epack[p] = make_int2(r, __float_as_int(dinv[r]));
}

// W [K][N] fp32 -> transposed split bf16 WT{h,l} [N][K] (weights stay exact)
__global__ void k_prepW(const float* __restrict__ W,
                        unsigned short* __restrict__ Th,
                        unsigned short* __restrict__ Tl, int K, int N) {
    int idx = blockIdx.x * blockDim.x + threadIdx.x;
    if (idx >= K * N) return;
    int n = idx / K, k = idx - n * K;
    float v = W[(size_t)k * N + n];
    unsigned short h = f2bf(v);
    Th[idx] = h;
    Tl[idx] = f2bf(v - bf2f(h));
}

// x fp32 -> bf16 (row-major)
__global__ void k_prepX(const float* __restrict__ x, unsigned short* __restrict__ xb) {
    int i = blockIdx.x * blockDim.x + threadIdx.x;
    if (i < N_NODES * 128) xb[i] = f2bf(x[i]);
}

// ---------------------------------------------------------------------------
// Paired-gather wave-per-node aggregation:
//   res[v] = dinv[v] * ( x[v]*dinv[v] + sum_j x[r_j]*dinv[r_j] )
// One wave owns one node; each gather INSTRUCTION covers SEG edges at
// 16B/lane (DIM=256: 2 edges x 32 lanes; DIM=128: 4 edges x 16 lanes).
// Cost model (R3/R7/R9/R10): instr ~= max(77cyc, 10cyc x 128B-granules);
// 2x512B = 8 granules -> ~80cyc for 2 edges = 2x throughput vs R10.
// Half-wave partials combined once per node via __shfl_xor.
// POOL=0: row-major bf16 out. POOL=1: bias+relu+bucketed mean-pool.
template <int DIM, int POOL>
__global__ __launch_bounds__(256) void k_aggw2(
    const unsigned short* __restrict__ xb, const int* __restrict__ off,
    const int2* __restrict__ epack, const float* __restrict__ dinv,
    const float* __restrict__ bias, unsigned short* __restrict__ outb,
    float* __restrict__ gb) {
    const int LPE = DIM / 8;      // lanes per edge-row (32 or 16)
    const int SEG = 64 / LPE;     // edges per gather instruction (2 or 4)
    __shared__ float gpart[256];
    if (POOL) {
        gpart[threadIdx.x] = 0.0f;
        __syncthreads();
    }
    int wv = threadIdx.x >> 6;        // wave in block
    int li = threadIdx.x & 63;        // lane
    int v = blockIdx.x * 4 + wv;      // node (grid divides N exactly)
    int sub = li / LPE;               // edge slot within instruction
    int fl = (li % LPE) * 8;          // feature base of this lane
    float dv = dinv[v];
    const unsigned short* __restrict__ xf = xb + fl;
    float aA[8], aB[8];
#pragma unroll
    for (int i = 0; i < 8; ++i) { aA[i] = 0.f; aB[i] = 0.f; }
    // self-loop: sub-group 0 only (single segment, predicated)
    if (sub == 0) {
        uint4 sv = *(const uint4*)&xf[(size_t)v * DIM];
        accum8(aA, sv, dv);
    }
    int s = off[v], e = off[v + 1];
    int j = s;
    // main: 2 instructions (2*SEG edges) per iteration, independent banks
    for (; j + 2 * SEG <= e; j += 2 * SEG) {
        int2 p0 = epack[j + sub];
        int2 p1 = epack[j + SEG + sub];
        uint4 g0 = *(const uint4*)&xf[(size_t)p0.x * DIM];
        uint4 g1 = *(const uint4*)&xf[(size_t)p1.x * DIM];
        accum8(aA, g0, __int_as_float(p0.y));
        accum8(aB, g1, __int_as_float(p1.y));
    }
    // tail: one predicated instruction at a time
    for (; j < e; j += SEG) {
        int je = j + sub;
        if (je < e) {
            int2 p = epack[je];
            uint4 g = *(const uint4*)&xf[(size_t)p.x * DIM];
            accum8(aA, g, __int_as_float(p.y));
        }
    }
    float acc[8];
#pragma unroll
    for (int i = 0; i < 8; ++i) acc[i] = aA[i] + aB[i];
    // combine sub-group partials (all lanes end with the full sum)
    if (SEG >= 4) {
#pragma unroll
        for (int i = 0; i < 8; ++i) acc[i] += __shfl_xor(acc[i], 16, 64);
    }
#pragma unroll
    for (int i = 0; i < 8; ++i) acc[i] += __shfl_xor(acc[i], 32, 64);
#pragma unroll
    for (int i = 0; i < 8; ++i) acc[i] *= dv;
    if (!POOL) {
        if (sub == 0) {
            uint4 o;
            o.x = (unsigned)f2bf(acc[0]) | ((unsigned)f2bf(acc[1]) << 16);
            o.y = (unsigned)f2bf(acc[2]) | ((unsigned)f2bf(acc[3]) << 16);
            o.z = (unsigned)f2bf(acc[4]) | ((unsigned)f2bf(acc[5]) << 16);
            o.w = (unsigned)f2bf(acc[6]) | ((unsigned)f2bf(acc[7]) << 16);
            *(uint4*)&outb[(size_t)v * DIM + fl] = o;
        }
    } else {
        if (sub == 0) {
#pragma unroll
            for (int i = 0; i < 8; ++i) {
                float r = fmaxf(acc[i] + bias[fl + i], 0.0f);
                atomicAdd(&gpart[fl + i], r);
            }
        }
        __syncthreads();
        atomicAdd(&gb[(blockIdx.x & (N_BUCKETS - 1)) * 256 + threadIdx.x],
                  gpart[threadIdx.x]);
    }
}

// ---------------------------------------------------------------------------
// bf16-A x split-bf16-B MFMA GEMM: C[M,N] = A[M,K] @ (Bh+Bl)[K,N] (+bias)(relu)
// B pre-transposed [N][K]. 128x128 tile, BK=32, double-buffered LDS.
// LDS k-chunks swizzled by (row>>1)&3 to break the 64B-row-stride conflicts.
template <int BIAS, int RELU>
__global__ __launch_bounds__(256) void k_gemm_b(
    const unsigned short* __restrict__ A,
    const unsigned short* __restrict__ Bh, const unsigned short* __restrict__ Bl,
    const float* __restrict__ bias, unsigned short* __restrict__ C,
    int M, int K, int N) {
    __shared__ unsigned short As[2][128 * 32];
    __shared__ unsigned short BsH[2][128 * 32];
    __shared__ unsigned short BsL[2][128 * 32];
    int tid = threadIdx.x;
    int lane = tid & 63;
    int w = tid >> 6;
    int wr = w & 1, wc = w >> 1;
    int bm = blockIdx.x * 128, bn = blockIdx.y * 128;

    floatx4 acc[4][4];
    floatx4 zero = {0.f, 0.f, 0.f, 0.f};
#pragma unroll
    for (int t = 0; t < 4; ++t)
#pragma unroll
        for (int u = 0; u < 4; ++u) acc[t][u] = zero;

    int c0 = w * 2, c1 = c0 + 1;
    int srow = lane >> 2;
    int kg = ((lane & 3) - ((lane >> 3) & 3)) & 3;  // global k-chunk (inverse swizzle)
    int kc = kg * 8;
    const unsigned short* Ap0 = A + (size_t)(bm + c0 * 16 + srow) * K + kc;
    const unsigned short* Ap1 = A + (size_t)(bm + c1 * 16 + srow) * K + kc;
    const unsigned short* Bh0 = Bh + (size_t)(bn + c0 * 16 + srow) * K + kc;
    const unsigned short* Bh1 = Bh + (size_t)(bn + c1 * 16 + srow) * K + kc;
    const unsigned short* Bl0 = Bl + (size_t)(bn + c0 * 16 + srow) * K + kc;
    const unsigned short* Bl1 = Bl + (size_t)(bn + c1 * 16 + srow) * K + kc;

    const int KT = K >> 5;
#define STAGE(half, k0)                                   \
    do {                                                  \
        gload16(Ap0 + (k0), &As[half][c0 * 512]);         \
        gload16(Ap1 + (k0), &As[half][c1 * 512]);         \
        gload16(Bh0 + (k0), &BsH[half][c0 * 512]);        \
        gload16(Bh1 + (k0), &BsH[half][c1 * 512]);        \
        gload16(Bl0 + (k0), &BsL[half][c0 * 512]);        \
        gload16(Bl1 + (k0), &BsL[half][c1 * 512]);        \
    } while (0)

    STAGE(0, 0);
    __syncthreads();

    int fr = lane & 15;            // m (A) / n (B) within 16-tile
    int fq = lane >> 4;            // k-chunk 0..3
    int cl = ((fq + (fr >> 1)) & 3) * 8;  // swizzled LDS k-chunk offset

    for (int kt = 0; kt < KT; ++kt) {
        int half = kt & 1;
        if (kt + 1 < KT) STAGE(1 - half, (kt + 1) * 32);
        short8 av[4], bhv[4], blv[4];
#pragma unroll
        for (int t = 0; t < 4; ++t) {
            av[t]  = *(const short8*)&As[half][(wr * 64 + t * 16 + fr) * 32 + cl];
            bhv[t] = *(const short8*)&BsH[half][(wc * 64 + t * 16 + fr) * 32 + cl];
            blv[t] = *(const short8*)&BsL[half][(wc * 64 + t * 16 + fr) * 32 + cl];
        }
#pragma unroll
        for (int t = 0; t < 4; ++t)
#pragma unroll
            for (int u = 0; u < 4; ++u) {
                acc[t][u] = __builtin_amdgcn_mfma_f32_16x16x32_bf16(av[t], bhv[u], acc[t][u], 0, 0, 0);
                acc[t][u] = __builtin_amdgcn_mfma_f32_16x16x32_bf16(av[t], blv[u], acc[t][u], 0, 0, 0);
            }
        __syncthreads();
    }
#undef STAGE

    // epilogue: C/D layout col = lane&15, row = (lane>>4)*4 + reg
#pragma unroll
    for (int u = 0; u < 4; ++u) {
        int colg = bn + wc * 64 + u * 16 + fr;
        float bv = BIAS ? bias[colg] : 0.0f;
#pragma unroll
        for (int t = 0; t < 4; ++t) {
#pragma unroll
            for (int r = 0; r < 4; ++r) {
                int rowg = bm + wr * 64 + t * 16 + fq * 4 + r;
                if (rowg < M) {
                    float o = acc[t][u][r] + bv;
                    if (RELU) o = fmaxf(o, 0.f);
                    C[(size_t)rowg * N + colg] = f2bf(o);
                }
            }
        }
    }
}

// tiny MLP; first reduces the 64 pool buckets
__global__ void k_mlp(const float* __restrict__ gb,
                      const float* __restrict__ Wf1, const float* __restrict__ bf1,
                      const float* __restrict__ Wf2, const float* __restrict__ bf2,
                      const float* __restrict__ Wf3, const float* __restrict__ bf3,
                      float* __restrict__ out) {
    __shared__ float s0[256], s1[128], s2[64];
    int t = threadIdx.x;
    float sum = 0.0f;
    for (int b = 0; b < N_BUCKETS; ++b) sum += gb[b * 256 + t];
    s0[t] = sum * (1.0f / (float)N_NODES);
    __syncthreads();
    if (t < 128) {
        float a = bf1[t];
        for (int k = 0; k < 256; ++k) a += s0[k] * Wf1[k * 128 + t];
        s1[t] = fmaxf(a, 0.0f);
    }
    __syncthreads();
    if (t < 64) {
        float a = bf2[t];
        for (int k = 0; k < 128; ++k) a += s1[k] * Wf2[k * 64 + t];
        s2[t] = fmaxf(a, 0.0f);
    }
    __syncthreads();
    if (t == 0) {
        float a = bf3[0];
        for (int k = 0; k < 64; ++k) a += s2[k] * Wf3[k];
        out[0] = a;
    }
}

extern "C" void kernel_launch(void* const* d_in, const int* in_sizes, int n_in,
                              void* d_out, int out_size, void* d_ws, size_t ws_size,
                              hipStream_t stream) {
    const float* x  = (const float*)d_in[0];
    const int* ei   = (const int*)d_in[1];
    const float* W1 = (const float*)d_in[2];
    const float* b1 = (const float*)d_in[3];
    const float* W2 = (const float*)d_in[4];
    const float* b2 = (const float*)d_in[5];
    const float* W3 = (const float*)d_in[6];
    const float* b3 = (const float*)d_in[7];
    const float* Wf1 = (const float*)d_in[8];
    const float* bf1 = (const float*)d_in[9];
    const float* Wf2 = (const float*)d_in[10];
    const float* bf2 = (const float*)d_in[11];
    const float* Wf3 = (const float*)d_in[12];
    const float* bf3 = (const float*)d_in[13];
    float* out = (float*)d_out;

    char* p = (char*)d_ws;
    auto alloc = [&](size_t bytes) {
        void* r = (void*)p;
        p += (bytes + 255) & ~((size_t)255);
        return r;
    };
    int*   cnt    = (int*)  alloc(N_NODES * sizeof(int));
    int*   off    = (int*)  alloc((N_NODES + 1) * sizeof(int));
    int*   cursor = (int*)  alloc(N_NODES * sizeof(int));
    int*   bsum   = (int*)  alloc(SCAN_NB * sizeof(int));
    int*   bbase  = (int*)  alloc(SCAN_NB * sizeof(int));
    float* dinv   = (float*)alloc(N_NODES * sizeof(float));
    int2*  epack  = (int2*) alloc((size_t)N_EDGES * sizeof(int2));
    float* gb     = (float*)alloc(N_BUCKETS * 256 * sizeof(float));
    unsigned short* W1h = (unsigned short*)alloc(128 * 256 * 2);
    unsigned short* W1l = (unsigned short*)alloc(128 * 256 * 2);
    unsigned short* W2h = (unsigned short*)alloc(256 * 512 * 2);
    unsigned short* W2l = (unsigned short*)alloc(256 * 512 * 2);
    unsigned short* W3h = (unsigned short*)alloc(512 * 256 * 2);
    unsigned short* W3l = (unsigned short*)alloc(512 * 256 * 2);
    unsigned short* xb = (unsigned short*)alloc((size_t)N_NODES * 128 * 2);
    unsigned short* t0 = (unsigned short*)alloc((size_t)M_PAD * 128 * 2);
    unsigned short* h1 = (unsigned short*)alloc((size_t)N_NODES * 256 * 2);
    unsigned short* t1 = (unsigned short*)alloc((size_t)M_PAD * 256 * 2);
    unsigned short* h2 = (unsigned short*)alloc((size_t)M_PAD * 512 * 2);
    unsigned short* t2 = (unsigned short*)alloc((size_t)N_NODES * 256 * 2);

    const int* row = ei;
    const int* col = ei + N_EDGES;

    const int NB = (N_NODES + 255) / 256;  // 196
    const int EB = (N_EDGES + 255) / 256;

    // CSR build + norm (hierarchical scan)
    k_init<<<NB, 256, 0, stream>>>(cnt, gb);
    k_count<<<EB, 256, 0, stream>>>(col, cnt);
    k_scanA<<<SCAN_NB, 256, 0, stream>>>(cnt, bsum);
    k_scanB<<<1, 256, 0, stream>>>(bsum, bbase, off);
    k_scanC<<<SCAN_NB, 256, 0, stream>>>(cnt, bbase, off, cursor, dinv);
    k_fill<<<EB, 256, 0, stream>>>(row, col, dinv, cursor, epack);

    // weight prep (transpose + exact split) and x -> bf16
    k_prepW<<<(128 * 256 + 255) / 256, 256, 0, stream>>>(W1, W1h, W1l, 128, 256);
    k_prepW<<<(256 * 512 + 255) / 256, 256, 0, stream>>>(W2, W2h, W2l, 256, 512);
    k_prepW<<<(512 * 256 + 255) / 256, 256, 0, stream>>>(W3, W3h, W3l, 512, 256);
    k_prepX<<<(N_NODES * 128 + 255) / 256, 256, 0, stream>>>(x, xb);

    const int M = N_NODES;
    const int MB = (M + 127) / 128; // 391

    // conv1: t0 = agg(xb); h1 = relu(t0@W1 + b1)
    k_aggw2<128, 0><<<N_NODES / 4, 256, 0, stream>>>(
        xb, off, epack, dinv, nullptr, t0, nullptr);
    {
        dim3 grid(MB, 256 / 128);
        k_gemm_b<1, 1><<<grid, 256, 0, stream>>>(t0, W1h, W1l, b1, h1, M, 128, 256);
    }
    // conv2: t1 = agg(h1); h2 = relu(t1@W2 + b2)
    k_aggw2<256, 0><<<N_NODES / 4, 256, 0, stream>>>(
        h1, off, epack, dinv, nullptr, t1, nullptr);
    {
        dim3 grid(MB, 512 / 128);
        k_gemm_b<1, 1><<<grid, 256, 0, stream>>>(t1, W2h, W2l, b2, h2, M, 256, 512);
    }
    // conv3: t2 = h2@W3; fused agg + bias + relu + bucketed mean-pool
    {
        dim3 grid(MB, 256 / 128);
        k_gemm_b<0, 0><<<grid, 256, 0, stream>>>(h2, W3h, W3l, nullptr, t2, M, 512, 256);
    }
    k_aggw2<256, 1><<<N_NODES / 4, 256, 0, stream>>>(
        t2, off, epack, dinv, b3, nullptr, gb);

    // MLP (reduces buckets internally)
    k_mlp<<<1, 256, 0, stream>>>(gb, Wf1, bf1, Wf2, bf2, Wf3, bf3, out);
}